// Round 8
// baseline (90.616 us; speedup 1.0000x reference)
//
#include <hip/hip_runtime.h>
#include <math.h>

// LocalContrastNormalization: out = sigmoid(0.5*(x-mu)/(sigma+eps)),
// mu/sigma from 31x31 zero-padded box filter (separable).
// v8 = v7 (SH=64, NT=512, transposed LDS, full-row stores) + latency hiding:
//   per phase: publish+slide (loads already resident -> no VMEM stall)
//              -> bar1 -> ISSUE next phase's slide loads + this x-row
//              -> horizontal (61 LDS reads + pointwise hides the HBM latency)
//              -> stores -> bar2 (drain waits on mostly-landed loads).
//   Wave-uniform fast path skips clamp+mask except at image edges.

#define KSZ    31
#define PAD    15
#define IMG_H  1024
#define IMG_W  1024
#define SH     64                // rows per block
#define RPP    8                 // rows per phase == waves per block
#define PHASES (SH / RPP)        // 8
#define NT     512
#define LROW   66                // transposed stride in float2 units
#define LBUF   (16 * LROW)       // 1056 float2 per row-buffer
#define EPSV   1e-5f

__global__ __launch_bounds__(NT, 4)
void lcn_fused_kernel(const float* __restrict__ x, float* __restrict__ out) {
    // XCD-aware bijective swizzle (gridDim.x = 512, %8==0).
    const int cpx = gridDim.x >> 3;
    const int bid = (blockIdx.x & 7) * cpx + (blockIdx.x >> 3);

    const int chunk = bid & 15;            // 16 chunks of 64 rows per image
    const int b     = bid >> 4;
    const int y0    = chunk * SH;

    const float* img  = x   + (size_t)b * (IMG_H * IMG_W);
    float*       oimg = out + (size_t)b * (IMG_H * IMG_W);

    __shared__ float2 vbuf[RPP][LBUF];     // (vsum, vsumsq), transposed

    const int t    = threadIdx.x;
    const int wave = t >> 6;               // 0..7
    const int lane = t & 63;

    // Zero only the pads; interior republished every phase. Phase-0 bar1
    // orders these before any horizontal read.
    for (int i = t; i < RPP * 32; i += NT) {
        const int r = i >> 5, k = i & 31;
        float2* vb = vbuf[r];
        if (k < 16) vb[k * LROW] = make_float2(0.f, 0.f);
        else        vb[(k - 16) * LROW + (LROW - 1)] = make_float2(0.f, 0.f);
    }

    // ---- vertical warm-up: window(y0) over rows [y0-15, y0+15] ----
    const int c0 = 2 * t;                  // 2 consecutive cols per thread
    float vs0 = 0.f, vs1 = 0.f, vq0 = 0.f, vq1 = 0.f;
    for (int y = y0 - PAD; y <= y0 + PAD; ++y) {
        const int yc = max(y, 0);
        float2 v = *(const float2*)(img + (size_t)yc * IMG_W + c0);
        const float m = (y >= 0) ? 1.f : 0.f;
        v.x *= m; v.y *= m;
        vs0 += v.x; vq0 = fmaf(v.x, v.x, vq0);
        vs1 += v.y; vq1 = fmaf(v.y, v.y, vq1);
    }

    // ---- prologue: slide rows for phase 0 (masked path, runs once) ----
    float2 sb[RPP], ad[RPP];
    #pragma unroll
    for (int r = 0; r < RPP; ++r) {
        const int ys  = y0 + r - PAD;
        const int ya  = y0 + r + PAD + 1;      // <= y0+23 <= 983: never clips
        const int ysc = max(ys, 0);
        float2 vS = *(const float2*)(img + (size_t)ysc * IMG_W + c0);
        float2 vA = *(const float2*)(img + (size_t)ya  * IMG_W + c0);
        const float mS = (ys >= 0) ? 1.f : 0.f;
        sb[r] = make_float2(vS.x * mS, vS.y * mS);
        ad[r] = vA;
    }

    // Transposed publish indices for iv = c0+16, c0+17.
    const int iv0 = c0 + 16;
    const int wp0 = ((iv0    ) & 15) * LROW + ((iv0    ) >> 4);
    const int wp1 = ((iv0 + 1) & 15) * LROW + ((iv0 + 1) >> 4);

    const int   cbase = lane << 4;         // horizontal: 16 contiguous cols
    const float inv   = 1.0f / 961.0f;

    for (int ph = 0; ph < PHASES; ++ph) {
        const int yo = y0 + ph * RPP;

        // ---- publish + apply slides (sb/ad resident: no VMEM stall) ----
        #pragma unroll
        for (int r = 0; r < RPP; ++r) {
            vbuf[r][wp0] = make_float2(vs0, vq0);
            vbuf[r][wp1] = make_float2(vs1, vq1);
            vs0 += ad[r].x - sb[r].x;
            vq0 = fmaf(ad[r].x, ad[r].x, vq0); vq0 = fmaf(-sb[r].x, sb[r].x, vq0);
            vs1 += ad[r].y - sb[r].y;
            vq1 = fmaf(ad[r].y, ad[r].y, vq1); vq1 = fmaf(-sb[r].y, sb[r].y, vq1);
        }
        __syncthreads();

        // ---- issue NEXT phase's slide loads (consumed next publish) ----
        if (ph < PHASES - 1) {
            const int yn = yo + RPP;
            if (yn >= PAD && yn <= IMG_H - RPP - PAD - 1) {   // no clipping
                #pragma unroll
                for (int r = 0; r < RPP; ++r) {
                    sb[r] = *(const float2*)(img + (size_t)(yn + r - PAD) * IMG_W + c0);
                    ad[r] = *(const float2*)(img + (size_t)(yn + r + PAD + 1) * IMG_W + c0);
                }
            } else {                                          // edge phases
                #pragma unroll
                for (int r = 0; r < RPP; ++r) {
                    const int ys  = yn + r - PAD;
                    const int ya  = yn + r + PAD + 1;
                    const int ysc = max(ys, 0);
                    const int yac = min(ya, IMG_H - 1);
                    float2 vS = *(const float2*)(img + (size_t)ysc * IMG_W + c0);
                    float2 vA = *(const float2*)(img + (size_t)yac * IMG_W + c0);
                    const float mS = (ys >= 0)    ? 1.f : 0.f;
                    const float mA = (ya < IMG_H) ? 1.f : 0.f;
                    sb[r] = make_float2(vS.x * mS, vS.y * mS);
                    ad[r] = make_float2(vA.x * mA, vA.y * mA);
                }
            }
        }

        // ---- horizontal sliding window + pointwise (wave w -> row yo+w) ----
        {
            const int row = yo + wave;
            // x-row issued early too; consumed after the warm-up reads.
            const float* xr = img + (size_t)row * IMG_W + cbase;
            float4 xa = ((const float4*)xr)[0];
            float4 xb = ((const float4*)xr)[1];
            float4 xc = ((const float4*)xr)[2];
            float4 xd = ((const float4*)xr)[3];

            const float2* vr = &vbuf[wave][lane];
            float hs = 0.f, hq = 0.f;
            #pragma unroll
            for (int s = 1; s <= 31; ++s) {
                float2 v = vr[(s & 15) * LROW + (s >> 4)];
                hs += v.x; hq += v.y;
            }
            float xs[16] = { xa.x, xa.y, xa.z, xa.w,  xb.x, xb.y, xb.z, xb.w,
                             xc.x, xc.y, xc.z, xc.w,  xd.x, xd.y, xd.z, xd.w };
            float res[16];
            #pragma unroll
            for (int j = 0; j < 16; ++j) {
                if (j > 0) {
                    float2 va  = vr[((j - 1) & 15) * LROW + 2];
                    float2 vsu = vr[(j & 15) * LROW];
                    hs += va.x - vsu.x;
                    hq += va.y - vsu.y;
                }
                const float mean = hs * inv;
                const float var  = fmaf(-mean, mean, hq * inv);
                const float stdv = sqrtf(fmaxf(var, EPSV));
                const float norm = (xs[j] - mean) *
                                   __builtin_amdgcn_rcpf(stdv + EPSV);
                res[j] = __builtin_amdgcn_rcpf(1.0f + __expf(-0.5f * norm));
            }
            float* orow = oimg + (size_t)row * IMG_W + cbase;
            ((float4*)orow)[0] = make_float4(res[0],  res[1],  res[2],  res[3]);
            ((float4*)orow)[1] = make_float4(res[4],  res[5],  res[6],  res[7]);
            ((float4*)orow)[2] = make_float4(res[8],  res[9],  res[10], res[11]);
            ((float4*)orow)[3] = make_float4(res[12], res[13], res[14], res[15]);
        }
        __syncthreads();                   // WAR: buffers rewritten next phase
    }
}

extern "C" void kernel_launch(void* const* d_in, const int* in_sizes, int n_in,
                              void* d_out, int out_size, void* d_ws, size_t ws_size,
                              hipStream_t stream) {
    (void)n_in; (void)out_size; (void)d_ws; (void)ws_size;
    const float* x = (const float*)d_in[0];
    float* out = (float*)d_out;
    const int B = in_sizes[0] / (IMG_H * IMG_W);   // 32
    dim3 grid(B * (IMG_H / SH));                   // 512 blocks
    lcn_fused_kernel<<<grid, NT, 0, stream>>>(x, out);
}

// Round 9
// 90.245 us; speedup vs baseline: 1.0041x; 1.0041x over previous
//
#include <hip/hip_runtime.h>
#include <math.h>

// LocalContrastNormalization: out = sigmoid(0.5*(x-mu)/(sigma+eps)),
// mu/sigma from 31x31 zero-padded box filter (separable).
// v9 = v8 (SH=64, NT=512, transposed LDS, full-row stores, next-phase
// prefetch during horizontal) with ONE change: RAW BARRIERS.
// __syncthreads() emits s_waitcnt vmcnt(0) before s_barrier, force-draining
// the prefetched slide loads every phase (the m97 structural stall). The
// in-flight global loads target private registers only, so the barriers
// need only LDS ordering: s_waitcnt lgkmcnt(0) + s_barrier. Prefetched
// loads now survive across phases -> HBM pipe stays continuously fed.

#define KSZ    31
#define PAD    15
#define IMG_H  1024
#define IMG_W  1024
#define SH     64                // rows per block
#define RPP    8                 // rows per phase == waves per block
#define PHASES (SH / RPP)        // 8
#define NT     512
#define LROW   66                // transposed stride in float2 units
#define LBUF   (16 * LROW)       // 1056 float2 per row-buffer
#define EPSV   1e-5f

// LDS-only barrier: order ds_write/ds_read across waves WITHOUT draining
// in-flight global loads (they only feed private registers).
#define LDS_BARRIER() do {                                   \
    asm volatile("s_waitcnt lgkmcnt(0)" ::: "memory");       \
    __builtin_amdgcn_s_barrier();                            \
} while (0)

__global__ __launch_bounds__(NT, 4)
void lcn_fused_kernel(const float* __restrict__ x, float* __restrict__ out) {
    // XCD-aware bijective swizzle (gridDim.x = 512, %8==0).
    const int cpx = gridDim.x >> 3;
    const int bid = (blockIdx.x & 7) * cpx + (blockIdx.x >> 3);

    const int chunk = bid & 15;            // 16 chunks of 64 rows per image
    const int b     = bid >> 4;
    const int y0    = chunk * SH;

    const float* img  = x   + (size_t)b * (IMG_H * IMG_W);
    float*       oimg = out + (size_t)b * (IMG_H * IMG_W);

    __shared__ float2 vbuf[RPP][LBUF];     // (vsum, vsumsq), transposed

    const int t    = threadIdx.x;
    const int wave = t >> 6;               // 0..7
    const int lane = t & 63;

    // Zero only the pads; interior republished every phase. Phase-0's
    // first LDS_BARRIER orders these before any horizontal read.
    for (int i = t; i < RPP * 32; i += NT) {
        const int r = i >> 5, k = i & 31;
        float2* vb = vbuf[r];
        if (k < 16) vb[k * LROW] = make_float2(0.f, 0.f);
        else        vb[(k - 16) * LROW + (LROW - 1)] = make_float2(0.f, 0.f);
    }

    // ---- vertical warm-up: window(y0) over rows [y0-15, y0+15] ----
    const int c0 = 2 * t;                  // 2 consecutive cols per thread
    float vs0 = 0.f, vs1 = 0.f, vq0 = 0.f, vq1 = 0.f;
    for (int y = y0 - PAD; y <= y0 + PAD; ++y) {
        const int yc = max(y, 0);
        float2 v = *(const float2*)(img + (size_t)yc * IMG_W + c0);
        const float m = (y >= 0) ? 1.f : 0.f;
        v.x *= m; v.y *= m;
        vs0 += v.x; vq0 = fmaf(v.x, v.x, vq0);
        vs1 += v.y; vq1 = fmaf(v.y, v.y, vq1);
    }

    // ---- prologue: slide rows for phase 0 (masked path, runs once) ----
    float2 sb[RPP], ad[RPP];
    #pragma unroll
    for (int r = 0; r < RPP; ++r) {
        const int ys  = y0 + r - PAD;
        const int ya  = y0 + r + PAD + 1;      // <= y0+23 <= 983: never clips
        const int ysc = max(ys, 0);
        float2 vS = *(const float2*)(img + (size_t)ysc * IMG_W + c0);
        float2 vA = *(const float2*)(img + (size_t)ya  * IMG_W + c0);
        const float mS = (ys >= 0) ? 1.f : 0.f;
        sb[r] = make_float2(vS.x * mS, vS.y * mS);
        ad[r] = vA;
    }

    // Transposed publish indices for iv = c0+16, c0+17.
    const int iv0 = c0 + 16;
    const int wp0 = ((iv0    ) & 15) * LROW + ((iv0    ) >> 4);
    const int wp1 = ((iv0 + 1) & 15) * LROW + ((iv0 + 1) >> 4);

    const int   cbase = lane << 4;         // horizontal: 16 contiguous cols
    const float inv   = 1.0f / 961.0f;

    for (int ph = 0; ph < PHASES; ++ph) {
        const int yo = y0 + ph * RPP;

        // ---- publish + apply slides (sb/ad resident via compiler vmcnt) ----
        #pragma unroll
        for (int r = 0; r < RPP; ++r) {
            vbuf[r][wp0] = make_float2(vs0, vq0);
            vbuf[r][wp1] = make_float2(vs1, vq1);
            vs0 += ad[r].x - sb[r].x;
            vq0 = fmaf(ad[r].x, ad[r].x, vq0); vq0 = fmaf(-sb[r].x, sb[r].x, vq0);
            vs1 += ad[r].y - sb[r].y;
            vq1 = fmaf(ad[r].y, ad[r].y, vq1); vq1 = fmaf(-sb[r].y, sb[r].y, vq1);
        }
        LDS_BARRIER();   // RAW: publishes visible; loads stay in flight

        // ---- issue NEXT phase's slide loads (consumed next publish) ----
        if (ph < PHASES - 1) {
            const int yn = yo + RPP;
            if (yn >= PAD && yn <= IMG_H - RPP - PAD - 1) {   // no clipping
                #pragma unroll
                for (int r = 0; r < RPP; ++r) {
                    sb[r] = *(const float2*)(img + (size_t)(yn + r - PAD) * IMG_W + c0);
                    ad[r] = *(const float2*)(img + (size_t)(yn + r + PAD + 1) * IMG_W + c0);
                }
            } else {                                          // edge phases
                #pragma unroll
                for (int r = 0; r < RPP; ++r) {
                    const int ys  = yn + r - PAD;
                    const int ya  = yn + r + PAD + 1;
                    const int ysc = max(ys, 0);
                    const int yac = min(ya, IMG_H - 1);
                    float2 vS = *(const float2*)(img + (size_t)ysc * IMG_W + c0);
                    float2 vA = *(const float2*)(img + (size_t)yac * IMG_W + c0);
                    const float mS = (ys >= 0)    ? 1.f : 0.f;
                    const float mA = (ya < IMG_H) ? 1.f : 0.f;
                    sb[r] = make_float2(vS.x * mS, vS.y * mS);
                    ad[r] = make_float2(vA.x * mA, vA.y * mA);
                }
            }
        }

        // ---- horizontal sliding window + pointwise (wave w -> row yo+w) ----
        {
            const int row = yo + wave;
            const float* xr = img + (size_t)row * IMG_W + cbase;
            float4 xa = ((const float4*)xr)[0];
            float4 xb = ((const float4*)xr)[1];
            float4 xc = ((const float4*)xr)[2];
            float4 xd = ((const float4*)xr)[3];

            const float2* vr = &vbuf[wave][lane];
            float hs = 0.f, hq = 0.f;
            #pragma unroll
            for (int s = 1; s <= 31; ++s) {
                float2 v = vr[(s & 15) * LROW + (s >> 4)];
                hs += v.x; hq += v.y;
            }
            float xs[16] = { xa.x, xa.y, xa.z, xa.w,  xb.x, xb.y, xb.z, xb.w,
                             xc.x, xc.y, xc.z, xc.w,  xd.x, xd.y, xd.z, xd.w };
            float res[16];
            #pragma unroll
            for (int j = 0; j < 16; ++j) {
                if (j > 0) {
                    float2 va  = vr[((j - 1) & 15) * LROW + 2];
                    float2 vsu = vr[(j & 15) * LROW];
                    hs += va.x - vsu.x;
                    hq += va.y - vsu.y;
                }
                const float mean = hs * inv;
                const float var  = fmaf(-mean, mean, hq * inv);
                const float stdv = sqrtf(fmaxf(var, EPSV));
                const float norm = (xs[j] - mean) *
                                   __builtin_amdgcn_rcpf(stdv + EPSV);
                res[j] = __builtin_amdgcn_rcpf(1.0f + __expf(-0.5f * norm));
            }
            float* orow = oimg + (size_t)row * IMG_W + cbase;
            ((float4*)orow)[0] = make_float4(res[0],  res[1],  res[2],  res[3]);
            ((float4*)orow)[1] = make_float4(res[4],  res[5],  res[6],  res[7]);
            ((float4*)orow)[2] = make_float4(res[8],  res[9],  res[10], res[11]);
            ((float4*)orow)[3] = make_float4(res[12], res[13], res[14], res[15]);
        }
        LDS_BARRIER();   // WAR: reads done before next publish; no vmem drain
    }
}

extern "C" void kernel_launch(void* const* d_in, const int* in_sizes, int n_in,
                              void* d_out, int out_size, void* d_ws, size_t ws_size,
                              hipStream_t stream) {
    (void)n_in; (void)out_size; (void)d_ws; (void)ws_size;
    const float* x = (const float*)d_in[0];
    float* out = (float*)d_out;
    const int B = in_sizes[0] / (IMG_H * IMG_W);   // 32
    dim3 grid(B * (IMG_H / SH));                   // 512 blocks
    lcn_fused_kernel<<<grid, NT, 0, stream>>>(x, out);
}

// Round 10
// 85.440 us; speedup vs baseline: 1.0606x; 1.0562x over previous
//
#include <hip/hip_runtime.h>
#include <math.h>

// LocalContrastNormalization: out = sigmoid(0.5*(x-mu)/(sigma+eps)),
// mu/sigma from 31x31 zero-padded box filter (separable).
// v10: PRODUCER/CONSUMER WAVE SPECIALIZATION + double-buffered LDS.
//  - waves 4..7 (producers): per-thread 4-col vertical sliding sums for the
//    full 1024-wide row; publish group G_{p+1} (4 rows) into buf[(p+1)&1]
//    during phase p; slide loads PREFETCHED one full phase ahead and kept
//    in flight across the lgkm-only barriers.
//  - waves 0..3 (consumers): wave w processes row y0+4p+w from buf[p&1]:
//    31-read transposed-LDS warm-up (2-way ILP split) + 16-col register
//    sliding window + pointwise; compute-all-then-4-back-to-back-float4
//    stores (the proven exact-131MB epilogue).
//  - ONE lgkm-only barrier per phase (double buffer removes the WAR wait).
//  - LDS = 2 x 4 x 1056 float2 = 67.6 KB -> 2 blocks/CU; grid 512.

#define KSZ    31
#define PAD    15
#define IMG_H  1024
#define IMG_W  1024
#define SH     64                // rows per block
#define GP     4                 // rows per group/phase
#define NPH    (SH / GP)         // 16 phases
#define NT     512
#define LROW   66                // transposed stride in float2 units
#define LBUF   (16 * LROW)       // 1056 float2 per row-slot
#define EPSV   1e-5f

// LDS-only barrier: orders ds ops across waves WITHOUT draining in-flight
// global loads (they only feed private registers).
#define LDS_BARRIER() do {                                   \
    asm volatile("s_waitcnt lgkmcnt(0)" ::: "memory");       \
    __builtin_amdgcn_s_barrier();                            \
} while (0)

__global__ __launch_bounds__(NT, 4)
void lcn_fused_kernel(const float* __restrict__ x, float* __restrict__ out) {
    // XCD-aware bijective swizzle (gridDim.x = 512, %8==0).
    const int cpx = gridDim.x >> 3;
    const int bid = (blockIdx.x & 7) * cpx + (blockIdx.x >> 3);

    const int chunk = bid & 15;            // 16 chunks of 64 rows per image
    const int b     = bid >> 4;
    const int y0    = chunk * SH;

    const float* img  = x   + (size_t)b * (IMG_H * IMG_W);
    float*       oimg = out + (size_t)b * (IMG_H * IMG_W);

    __shared__ float2 vbuf[2][GP][LBUF];   // double-buffered, transposed

    const int t    = threadIdx.x;
    const int wave = t >> 6;               // 0..7
    const int lane = t & 63;

    // Pad init: 8 row-slots x 32 pad entries (iv<16 -> k*LROW; iv>=1040 ->
    // (k-16)*LROW+65). Done by consumer threads before their first barrier.
    if (t < 256) {
        const int s = t >> 5;              // slot 0..7
        const int k = t & 31;
        float2* vb = &vbuf[s >> 2][s & 3][0];
        if (k < 16) vb[k * LROW] = make_float2(0.f, 0.f);
        else        vb[(k - 16) * LROW + (LROW - 1)] = make_float2(0.f, 0.f);
    }

    const float inv = 1.0f / 961.0f;

    if (wave >= 4) {
        // ================= PRODUCER (waves 4..7) =================
        const int pt = t & 255;            // 0..255
        const int c0 = 4 * pt;             // 4 consecutive cols

        const int iv  = c0 + 16;
        const int wp0 = ((iv    ) & 15) * LROW + ((iv    ) >> 4);
        const int wp1 = ((iv + 1) & 15) * LROW + ((iv + 1) >> 4);
        const int wp2 = ((iv + 2) & 15) * LROW + ((iv + 2) >> 4);
        const int wp3 = ((iv + 3) & 15) * LROW + ((iv + 3) >> 4);

        // Warm-up: W(y0) over rows [y0-15, y0+15] (top never clips).
        float vs0=0,vs1=0,vs2=0,vs3=0, vq0=0,vq1=0,vq2=0,vq3=0;
        for (int y = y0 - PAD; y <= y0 + PAD; ++y) {
            const int yc = max(y, 0);
            float4 v = *(const float4*)(img + (size_t)yc * IMG_W + c0);
            const float m = (y >= 0) ? 1.f : 0.f;
            v.x *= m; v.y *= m; v.z *= m; v.w *= m;
            vs0 += v.x; vq0 = fmaf(v.x, v.x, vq0);
            vs1 += v.y; vq1 = fmaf(v.y, v.y, vq1);
            vs2 += v.z; vq2 = fmaf(v.z, v.z, vq2);
            vs3 += v.w; vq3 = fmaf(v.w, v.w, vq3);
        }

        // Prologue: publish G0 (rows y0..y0+3) into buf0, sliding directly.
        #pragma unroll
        for (int r = 0; r < GP; ++r) {
            vbuf[0][r][wp0] = make_float2(vs0, vq0);
            vbuf[0][r][wp1] = make_float2(vs1, vq1);
            vbuf[0][r][wp2] = make_float2(vs2, vq2);
            vbuf[0][r][wp3] = make_float2(vs3, vq3);
            const int ys  = y0 + r - PAD;
            const int ya  = y0 + r + PAD + 1;      // <= y0+19: never clips
            const int ysc = max(ys, 0);
            float4 vS = *(const float4*)(img + (size_t)ysc * IMG_W + c0);
            float4 vA = *(const float4*)(img + (size_t)ya  * IMG_W + c0);
            const float mS = (ys >= 0) ? 1.f : 0.f;
            float s0 = vS.x*mS, s1 = vS.y*mS, s2 = vS.z*mS, s3 = vS.w*mS;
            vs0 += vA.x - s0; vq0 = fmaf(vA.x, vA.x, vq0); vq0 = fmaf(-s0, s0, vq0);
            vs1 += vA.y - s1; vq1 = fmaf(vA.y, vA.y, vq1); vq1 = fmaf(-s1, s1, vq1);
            vs2 += vA.z - s2; vq2 = fmaf(vA.z, vA.z, vq2); vq2 = fmaf(-s2, s2, vq2);
            vs3 += vA.w - s3; vq3 = fmaf(vA.w, vA.w, vq3); vq3 = fmaf(-s3, s3, vq3);
        }

        // Prefetch slide rows for phase 0 (publish base y0+GP).
        float4 pfS[GP], pfA[GP];
        {
            const int base = y0 + GP;
            #pragma unroll
            for (int r = 0; r < GP; ++r) {
                const int ys = base + r - PAD;
                const int ya = base + r + PAD + 1;
                pfS[r] = *(const float4*)(img + (size_t)max(ys, 0) * IMG_W + c0);
                pfA[r] = *(const float4*)(img + (size_t)min(ya, IMG_H - 1) * IMG_W + c0);
            }
        }

        for (int p = 0; p < NPH; ++p) {
            LDS_BARRIER();
            if (p < NPH - 1) {
                const int base = y0 + GP * (p + 1);
                float2* dst = &vbuf[(p + 1) & 1][0][0];
                #pragma unroll
                for (int r = 0; r < GP; ++r) {
                    float2* d = dst + r * LBUF;
                    d[wp0] = make_float2(vs0, vq0);
                    d[wp1] = make_float2(vs1, vq1);
                    d[wp2] = make_float2(vs2, vq2);
                    d[wp3] = make_float2(vs3, vq3);
                    const int ys = base + r - PAD;
                    const int ya = base + r + PAD + 1;
                    const float mS = (ys >= 0)    ? 1.f : 0.f;
                    const float mA = (ya < IMG_H) ? 1.f : 0.f;
                    float s0 = pfS[r].x*mS, s1 = pfS[r].y*mS,
                          s2 = pfS[r].z*mS, s3 = pfS[r].w*mS;
                    float a0 = pfA[r].x*mA, a1 = pfA[r].y*mA,
                          a2 = pfA[r].z*mA, a3 = pfA[r].w*mA;
                    vs0 += a0 - s0; vq0 = fmaf(a0, a0, vq0); vq0 = fmaf(-s0, s0, vq0);
                    vs1 += a1 - s1; vq1 = fmaf(a1, a1, vq1); vq1 = fmaf(-s1, s1, vq1);
                    vs2 += a2 - s2; vq2 = fmaf(a2, a2, vq2); vq2 = fmaf(-s2, s2, vq2);
                    vs3 += a3 - s3; vq3 = fmaf(a3, a3, vq3); vq3 = fmaf(-s3, s3, vq3);
                }
                if (p < NPH - 2) {        // prefetch for next phase's publish
                    const int base2 = y0 + GP * (p + 2);
                    #pragma unroll
                    for (int r = 0; r < GP; ++r) {
                        const int ys = base2 + r - PAD;
                        const int ya = base2 + r + PAD + 1;
                        pfS[r] = *(const float4*)(img + (size_t)max(ys, 0) * IMG_W + c0);
                        pfA[r] = *(const float4*)(img + (size_t)min(ya, IMG_H - 1) * IMG_W + c0);
                    }
                }
            }
        }
    } else {
        // ================= CONSUMER (waves 0..3) =================
        const int cbase = lane << 4;       // 16 contiguous cols per lane

        for (int p = 0; p < NPH; ++p) {
            LDS_BARRIER();
            const int row = y0 + GP * p + wave;

            // x-row issued first; latency hidden under the LDS warm-up.
            const float* xr = img + (size_t)row * IMG_W + cbase;
            float4 xa = ((const float4*)xr)[0];
            float4 xb = ((const float4*)xr)[1];
            float4 xc = ((const float4*)xr)[2];
            float4 xd = ((const float4*)xr)[3];

            const float2* vr = &vbuf[p & 1][wave][lane];

            // Warm-up with 2-way ILP split (shortens the serial add chain).
            float hsA = 0.f, hqA = 0.f, hsB = 0.f, hqB = 0.f;
            #pragma unroll
            for (int s = 1; s <= 31; s += 2) {
                float2 va = vr[(s & 15) * LROW + (s >> 4)];
                hsA += va.x; hqA += va.y;
                if (s + 1 <= 31) {
                    float2 vb2 = vr[((s + 1) & 15) * LROW + ((s + 1) >> 4)];
                    hsB += vb2.x; hqB += vb2.y;
                }
            }
            float hs = hsA + hsB, hq = hqA + hqB;

            float xs[16] = { xa.x, xa.y, xa.z, xa.w,  xb.x, xb.y, xb.z, xb.w,
                             xc.x, xc.y, xc.z, xc.w,  xd.x, xd.y, xd.z, xd.w };
            float res[16];
            #pragma unroll
            for (int j = 0; j < 16; ++j) {
                if (j > 0) {
                    float2 va  = vr[((j - 1) & 15) * LROW + 2];   // iv=cbase+j+31
                    float2 vsu = vr[(j & 15) * LROW];             // iv=cbase+j
                    hs += va.x - vsu.x;
                    hq += va.y - vsu.y;
                }
                const float mean = hs * inv;
                const float var  = fmaf(-mean, mean, hq * inv);
                const float stdv = sqrtf(fmaxf(var, EPSV));
                const float norm = (xs[j] - mean) *
                                   __builtin_amdgcn_rcpf(stdv + EPSV);
                res[j] = __builtin_amdgcn_rcpf(1.0f + __expf(-0.5f * norm));
            }

            // Proven exact-131MB epilogue: 4 back-to-back float4 stores.
            float* orow = oimg + (size_t)row * IMG_W + cbase;
            ((float4*)orow)[0] = make_float4(res[0],  res[1],  res[2],  res[3]);
            ((float4*)orow)[1] = make_float4(res[4],  res[5],  res[6],  res[7]);
            ((float4*)orow)[2] = make_float4(res[8],  res[9],  res[10], res[11]);
            ((float4*)orow)[3] = make_float4(res[12], res[13], res[14], res[15]);
        }
    }
}

extern "C" void kernel_launch(void* const* d_in, const int* in_sizes, int n_in,
                              void* d_out, int out_size, void* d_ws, size_t ws_size,
                              hipStream_t stream) {
    (void)n_in; (void)out_size; (void)d_ws; (void)ws_size;
    const float* x = (const float*)d_in[0];
    float* out = (float*)d_out;
    const int B = in_sizes[0] / (IMG_H * IMG_W);   // 32
    dim3 grid(B * (IMG_H / SH));                   // 512 blocks
    lcn_fused_kernel<<<grid, NT, 0, stream>>>(x, out);
}